// Round 2
// baseline (492.054 us; speedup 1.0000x reference)
//
#include <hip/hip_runtime.h>

// LIF spiking layer forward: x (B,C,T) fp32 -> spikes (B,C,T) fp32.
// Recurrence per row r=(b,c):
//   rst   = spk_{t-1} * Vth[c]
//   mem_t = (mem_{t-1} - rst)*beta + x_t*alpha
//   spk_t = (mem_t - Vth[c] > 0) ? 1 : 0
// Bit-exact vs numpy: no FMA contraction; rst handled via select since
// 1.0*Vth == Vth exactly and mem - 0.0 == mem exactly.
//
// R1: occupancy is structurally 1 wave/CU (16384 rows = 256 waves), so all
// latency hiding must come from per-wave MLP. rocprof showed VGPR_Count=52,
// proving the compiler sank the double-buffer loads to their uses (a real
// 2-chunk pipeline needs >=85 VGPRs), serializing ~500-cycle HBM exposures
// per float4. Fix: 3 rotating chunk buffers (prefetch distance 2, ~30 loads
// in flight) pinned with sched_barrier(0) so neither IR passes nor the
// machine scheduler can sink the loads past the compute. Output stores are
// nontemporal so the write stream doesn't evict x from the 256 MB L3.
// R2: __builtin_nontemporal_store needs a native vector type, not HIP's
// float4 class -> store through ext_vector_type(4) reinterpret.

constexpr int T_LEN = 2000;
constexpr int NV    = 10;            // float4 per chunk
constexpr int CH    = NV * 4;        // 40 timesteps per chunk
constexpr int NC    = T_LEN / CH;    // 50 chunks
static_assert(NC % 3 == 2, "main loop does groups of 3 with a 2-chunk epilogue");

typedef float nfloat4 __attribute__((ext_vector_type(4)));  // native vec for nt-store

__device__ __forceinline__ void load_chunk(float4 (&buf)[NV], const float4* __restrict__ xr, int c) {
#pragma unroll
    for (int v = 0; v < NV; ++v) buf[v] = xr[c * NV + v];
}

__device__ __forceinline__ float lif_step(float xval, float alpha, float beta, float vth,
                                          float& mem, float& vdiff, bool& spk) {
#pragma clang fp contract(off)
    float xa = xval * alpha;                 // x_t * alpha (separate mul, like np)
    // Speculative both-branch update; bit-exact vs (mem - rst)*beta + xa:
    //   spk==1: rst = 1.0*Vth = Vth, mem-Vth == vdiff (computed last step)
    //   spk==0: rst = 0.0*Vth = 0.0, mem-0.0 == mem
    float p0 = mem   * beta;
    float p1 = vdiff * beta;
    float q0 = p0 + xa;
    float q1 = p1 + xa;
    mem   = spk ? q1 : q0;
    vdiff = mem - vth;
    spk   = vdiff > 0.0f;
    return spk ? 1.0f : 0.0f;
}

__device__ __forceinline__ void compute_chunk(const float4 (&buf)[NV], float4* __restrict__ orow, int c,
                                              float alpha, float beta, float vth,
                                              float& mem, float& vdiff, bool& spk) {
#pragma clang fp contract(off)
#pragma unroll
    for (int v = 0; v < NV; ++v) {
        float4 xv = buf[v];
        nfloat4 s;
        s.x = lif_step(xv.x, alpha, beta, vth, mem, vdiff, spk);
        s.y = lif_step(xv.y, alpha, beta, vth, mem, vdiff, spk);
        s.z = lif_step(xv.z, alpha, beta, vth, mem, vdiff, spk);
        s.w = lif_step(xv.w, alpha, beta, vth, mem, vdiff, spk);
        // Nontemporal: output is write-once; keep it from evicting x in L3.
        __builtin_nontemporal_store(s, reinterpret_cast<nfloat4*>(&orow[c * NV + v]));
    }
}

__global__ __launch_bounds__(64) void lif_fwd_kernel(const float* __restrict__ x,
                                                     const float* __restrict__ alpha_p,
                                                     const float* __restrict__ beta_p,
                                                     const float* __restrict__ vth_p,
                                                     float* __restrict__ out,
                                                     int C, int rows) {
#pragma clang fp contract(off)
    const int row = blockIdx.x * 64 + threadIdx.x;
    if (row >= rows) return;

    const float alpha = alpha_p[0];
    const float beta  = beta_p[0];
    const float vth   = vth_p[(unsigned)row % (unsigned)C];

    const float4* __restrict__ xr   = reinterpret_cast<const float4*>(x + (size_t)row * T_LEN);
    float4* __restrict__       orow = reinterpret_cast<float4*>(out + (size_t)row * T_LEN);

    float mem = 0.0f, vdiff = 0.0f;
    bool  spk = false;
    // vdiff init: only consumed when spk==true, so value irrelevant at t=0.

    float4 A[NV], B[NV], Cb[NV];

    // Prologue: chunks 0 and 1 in flight.
    load_chunk(A, xr, 0);
    load_chunk(B, xr, 1);
    __builtin_amdgcn_sched_barrier(0);

    // Rotating 3-buffer pipeline, prefetch distance 2. sched_barrier(0) pins
    // each load region ahead of the following compute so the loads stay in
    // flight (compiler cannot sink them past the barrier).
    int c = 0;
    for (int i = 0; i < NC / 3; ++i) {      // 16 iterations, chunks 0..47
        load_chunk(Cb, xr, c + 2);          // c+2 <= 47
        __builtin_amdgcn_sched_barrier(0);
        compute_chunk(A, orow, c, alpha, beta, vth, mem, vdiff, spk);

        load_chunk(A, xr, c + 3);           // c+3 <= 48 < NC always
        __builtin_amdgcn_sched_barrier(0);
        compute_chunk(B, orow, c + 1, alpha, beta, vth, mem, vdiff, spk);

        load_chunk(B, xr, c + 4);           // c+4 <= 49 < NC always
        __builtin_amdgcn_sched_barrier(0);
        compute_chunk(Cb, orow, c + 2, alpha, beta, vth, mem, vdiff, spk);

        c += 3;
    }
    // Epilogue: chunks 48 (A) and 49 (B) already loaded.
    compute_chunk(A, orow, c,     alpha, beta, vth, mem, vdiff, spk);
    compute_chunk(B, orow, c + 1, alpha, beta, vth, mem, vdiff, spk);
}

extern "C" void kernel_launch(void* const* d_in, const int* in_sizes, int n_in,
                              void* d_out, int out_size, void* d_ws, size_t ws_size,
                              hipStream_t stream) {
    const float* x     = (const float*)d_in[0];
    const float* alpha = (const float*)d_in[1];
    const float* beta  = (const float*)d_in[2];
    const float* vth   = (const float*)d_in[3];
    float* out = (float*)d_out;

    const int C    = in_sizes[3];            // 256
    const int rows = in_sizes[0] / T_LEN;    // B*C = 16384

    dim3 grid((rows + 63) / 64), block(64);
    lif_fwd_kernel<<<grid, block, 0, stream>>>(x, alpha, beta, vth, out, C, rows);
}

// Round 3
// 255.521 us; speedup vs baseline: 1.9257x; 1.9257x over previous
//
#include <hip/hip_runtime.h>

// LIF spiking layer forward: x (B,C,T) fp32 -> spikes (B,C,T) fp32.
// Recurrence per row r=(b,c):
//   rst   = spk_{t-1} * Vth[c]
//   mem_t = (mem_{t-1} - rst)*beta + x_t*alpha
//   spk_t = (mem_t - Vth[c] > 0) ? 1 : 0
// Bit-exact vs numpy: no FMA contraction; rst handled via select since
// 1.0*Vth == Vth exactly and mem - 0.0 == mem exactly.
//
// R1: occupancy is structurally 1 wave/CU (16384 rows = 256 waves) -> all
//     latency hiding must come from per-wave MLP.
// R2 post-mortem: nontemporal stores caused 3.5x HBM write amplification
//     (WRITE_SIZE 129->453 MB) -- reverted. sched_barrier(0) pinning failed:
//     VGPR=72 proves the IR-level sinker still collapsed the 3-buffer
//     pipeline (needs >=120 floats live).
// R3: hand-rolled pipeline with volatile inline-asm global_load_dwordx4
//     (cannot be sunk) + counted s_waitcnt vmcnt(N), AITER-style. 3 rotating
//     buffers, prefetch distance 2, 30 loads (30KB/CU) in flight. vmcnt
//     retires in-order; stores are fenced by the "memory" clobber on each
//     waitcnt asm, so steady-state wait is vmcnt(40) = (L(p+1),L(p+2),
//     S(p-2),S(p-1)) still allowed outstanding when L(p) must be complete.

constexpr int T_LEN = 2000;
constexpr int NV    = 10;            // float4 per chunk
constexpr int CH    = NV * 4;        // 40 timesteps per chunk
constexpr int NC    = T_LEN / CH;    // 50 chunks

typedef float nfloat4 __attribute__((ext_vector_type(4)));

// Volatile asm load: compiler cannot sink/elide it; result lands in a VGPR
// quad. All 10 loads of a chunk share one 64-bit base address register.
#define GL(dst, p, OFF) \
    asm volatile("global_load_dwordx4 %0, %1, off offset:" #OFF \
                 : "=v"(dst) : "v"(p))

#define LOAD_CHUNK(buf, p) do { \
    GL(buf[0], (p), 0);   GL(buf[1], (p), 16);  GL(buf[2], (p), 32); \
    GL(buf[3], (p), 48);  GL(buf[4], (p), 64);  GL(buf[5], (p), 80); \
    GL(buf[6], (p), 96);  GL(buf[7], (p), 112); GL(buf[8], (p), 128); \
    GL(buf[9], (p), 144); } while (0)

// Counted wait. "memory" clobber fences compiler stores (they cannot cross),
// keeping the issued-after-target-load op count exact. sched_barrier(0)
// stops the compiler hoisting register-only consumers above the wait
// (guide rule #18).
#define WAITV(N) do { \
    asm volatile("s_waitcnt vmcnt(" #N ")" ::: "memory"); \
    __builtin_amdgcn_sched_barrier(0); } while (0)

__device__ __forceinline__ float lif_step(float xval, float alpha, float beta, float vth,
                                          float& mem, float& vdiff, bool& spk) {
#pragma clang fp contract(off)
    float xa = xval * alpha;                 // x_t * alpha (separate mul, like np)
    // Speculative both-branch update; bit-exact vs (mem - rst)*beta + xa:
    //   spk==1: rst = 1.0*Vth = Vth, mem-Vth == vdiff (computed last step)
    //   spk==0: rst = 0.0*Vth = 0.0, mem-0.0 == mem
    float p0 = mem   * beta;
    float p1 = vdiff * beta;
    float q0 = p0 + xa;
    float q1 = p1 + xa;
    mem   = spk ? q1 : q0;
    vdiff = mem - vth;
    spk   = vdiff > 0.0f;
    return spk ? 1.0f : 0.0f;
}

__device__ __forceinline__ void compute_chunk(const nfloat4 (&buf)[NV], float4* __restrict__ orow, int c,
                                              float alpha, float beta, float vth,
                                              float& mem, float& vdiff, bool& spk) {
#pragma clang fp contract(off)
#pragma unroll
    for (int v = 0; v < NV; ++v) {
        nfloat4 xv = buf[v];
        float4 s;
        s.x = lif_step(xv.x, alpha, beta, vth, mem, vdiff, spk);
        s.y = lif_step(xv.y, alpha, beta, vth, mem, vdiff, spk);
        s.z = lif_step(xv.z, alpha, beta, vth, mem, vdiff, spk);
        s.w = lif_step(xv.w, alpha, beta, vth, mem, vdiff, spk);
        orow[c * NV + v] = s;                // plain store (nt was 3.5x worse)
    }
}

__global__ __launch_bounds__(64) void lif_fwd_kernel(const float* __restrict__ x,
                                                     const float* __restrict__ alpha_p,
                                                     const float* __restrict__ beta_p,
                                                     const float* __restrict__ vth_p,
                                                     float* __restrict__ out,
                                                     int C, int rows) {
#pragma clang fp contract(off)
    const int row = blockIdx.x * 64 + threadIdx.x;
    if (row >= rows) return;

    const float alpha = alpha_p[0];
    const float beta  = beta_p[0];
    const float vth   = vth_p[(unsigned)row % (unsigned)C];

    // Force the compiler's own vmcnt/lgkmcnt drain for alpha/beta/vth HERE,
    // before our asm loads, so the manual vmcnt counts start from zero.
    asm volatile("" :: "v"(alpha), "v"(beta), "v"(vth));

    const float4* __restrict__ xr   = reinterpret_cast<const float4*>(x + (size_t)row * T_LEN);
    float4* __restrict__       orow = reinterpret_cast<float4*>(out + (size_t)row * T_LEN);

    float mem = 0.0f, vdiff = 0.0f;
    bool  spk = false;
    // vdiff init: only consumed when spk==true, so value irrelevant at t=0.

    nfloat4 A[NV], B[NV], Cb[NV];

    // Prologue: chunks 0 and 1 in flight (20 loads).
    LOAD_CHUNK(A, xr);
    LOAD_CHUNK(B, xr + NV);

    // Peeled phases 0..2 (waits ramp 20 -> 30 -> 40).
    LOAD_CHUNK(Cb, xr + 2 * NV);
    WAITV(20);                                    // L0 done (L1,L2 in flight)
    compute_chunk(A, orow, 0, alpha, beta, vth, mem, vdiff, spk);

    LOAD_CHUNK(A, xr + 3 * NV);
    WAITV(30);                                    // L1 done (L2,S0,L3 allowed)
    compute_chunk(B, orow, 1, alpha, beta, vth, mem, vdiff, spk);

    LOAD_CHUNK(B, xr + 4 * NV);
    WAITV(40);                                    // L2 done (S0,L3,S1,L4 allowed)
    compute_chunk(Cb, orow, 2, alpha, beta, vth, mem, vdiff, spk);

    // Steady state: phases 3..47, 15 iterations x 3 phases.
    // Invariant at "compute chunk p": ops issued after L(p) are
    // S(p-2), L(p+1), S(p-1), L(p+2) = 40 -> vmcnt(40) guarantees L(p) done.
    int c = 3;
    for (int i = 0; i < 15; ++i) {
        LOAD_CHUNK(Cb, xr + (c + 2) * NV);
        WAITV(40);
        compute_chunk(A, orow, c, alpha, beta, vth, mem, vdiff, spk);

        LOAD_CHUNK(A, xr + (c + 3) * NV);
        WAITV(40);
        compute_chunk(B, orow, c + 1, alpha, beta, vth, mem, vdiff, spk);

        LOAD_CHUNK(B, xr + (c + 4) * NV);
        WAITV(40);
        compute_chunk(Cb, orow, c + 2, alpha, beta, vth, mem, vdiff, spk);

        c += 3;
    }
    // c == 48 here; A holds chunk 48, B holds chunk 49.
    WAITV(30);                                    // L48 done (S46,L49,S47 allowed)
    compute_chunk(A, orow, 48, alpha, beta, vth, mem, vdiff, spk);
    WAITV(20);                                    // L49 done (S47,S48 allowed)
    compute_chunk(B, orow, 49, alpha, beta, vth, mem, vdiff, spk);
}

extern "C" void kernel_launch(void* const* d_in, const int* in_sizes, int n_in,
                              void* d_out, int out_size, void* d_ws, size_t ws_size,
                              hipStream_t stream) {
    const float* x     = (const float*)d_in[0];
    const float* alpha = (const float*)d_in[1];
    const float* beta  = (const float*)d_in[2];
    const float* vth   = (const float*)d_in[3];
    float* out = (float*)d_out;

    const int C    = in_sizes[3];            // 256
    const int rows = in_sizes[0] / T_LEN;    // B*C = 16384

    dim3 grid((rows + 63) / 64), block(64);
    lif_fwd_kernel<<<grid, block, 0, stream>>>(x, alpha, beta, vth, out, C, rows);
}

// Round 6
// 250.144 us; speedup vs baseline: 1.9671x; 1.0215x over previous
//
#include <hip/hip_runtime.h>

// LIF spiking layer forward: x (B,C,T) fp32 -> spikes (B,C,T) fp32.
// Recurrence per row r=(b,c):
//   rst   = spk_{t-1} * Vth[c]
//   mem_t = (mem_{t-1} - rst)*beta + x_t*alpha
//   spk_t = (mem_t - Vth[c] > 0) ? 1 : 0
// Bit-exact vs numpy: no FMA contraction; rst via select (1.0*Vth == Vth,
// mem - 0.0 == mem).
//
// R1: occupancy structurally 1 wave/CU (16384 rows = 256 waves).
// R2: nt stores -> 3.5x HBM write amplification. Reverted.
// R3: asm-load pipeline w/ counted vmcnt: 103->97.6 us, absmax 0. Proved
//     loads are NOT the wall; write rate pinned at ~1.35 TB/s.
// R4: LDS transpose + asm stores -> garbage (asm stores consuming ds_read
//     results sit outside the compiler's waitcnt machinery).
// R5: LDS transpose + asm loads + plain stores -> GPU abort, cause not
//     located despite clean on-paper audit of addresses and vmcnt totals.
// R6: DECOUPLE. Same transpose (the actual theory under test: each store
//     instr = 8 rows x 128B contiguous full-line writes instead of 64x16B
//     scatter = 8x fewer write requests), but ZERO inline asm: plain C++
//     loads/LDS/stores; compiler owns all ordering and waitcnts. Outcome
//     splits: dur<<90us = theory confirmed; dur~100us w/ write-rate <<1.35
//     TB/s = loads collapsed (VGPR tells); dur~100us w/ rate ~1.35 = theory
//     dead. LDS rows stride 33 dwords: bank=(lane+t)%32 on writes, <=2-way
//     on transposed reads = conflict-free (2-way is free on CDNA4).

constexpr int T_LEN = 2000;
constexpr int CH    = 32;                      // timesteps per full tile
constexpr int NQ    = CH / 4;                  // 8 float4 per tile
constexpr int NFULL = 62;                      // 62*32 = 1984
constexpr int TAILQ = (T_LEN - NFULL * CH)/4;  // 4 quads = 16 steps
constexpr int LDSW  = 33;                      // LDS row stride (dwords)

__device__ __forceinline__ void load_tile(float4 (&buf)[NQ], const float4* __restrict__ p) {
#pragma unroll
    for (int q = 0; q < NQ; ++q) buf[q] = p[q];
}

__device__ __forceinline__ void load_tail(float4 (&buf)[NQ], const float4* __restrict__ p) {
#pragma unroll
    for (int q = 0; q < TAILQ; ++q) buf[q] = p[q];
}

__device__ __forceinline__ float lif_step(float xval, float alpha, float beta, float vth,
                                          float& mem, float& vdiff, bool& spk) {
#pragma clang fp contract(off)
    float xa = xval * alpha;             // x_t * alpha (separate mul, like np)
    // Speculative both-branch update; bit-exact vs (mem - rst)*beta + xa:
    //   spk==1: rst = 1.0*Vth = Vth, mem-Vth == vdiff (from last step)
    //   spk==0: rst = 0.0*Vth = 0.0, mem-0.0 == mem
    float p0 = mem   * beta;
    float p1 = vdiff * beta;
    float q0 = p0 + xa;
    float q1 = p1 + xa;
    mem   = spk ? q1 : q0;
    vdiff = mem - vth;
    spk   = vdiff > 0.0f;
    return spk ? 1.0f : 0.0f;
}

// Run N quads (4 steps each); write each spike scalar into this lane's LDS
// row. Single wave per block: DS ops execute in order, no barrier needed.
template <int N>
__device__ __forceinline__ void compute_tile(const float4 (&buf)[NQ], float* shrow,
                                             float alpha, float beta, float vth,
                                             float& mem, float& vdiff, bool& spk) {
#pragma clang fp contract(off)
#pragma unroll
    for (int q = 0; q < N; ++q) {
        float4 xv = buf[q];
        shrow[q*4 + 0] = lif_step(xv.x, alpha, beta, vth, mem, vdiff, spk);
        shrow[q*4 + 1] = lif_step(xv.y, alpha, beta, vth, mem, vdiff, spk);
        shrow[q*4 + 2] = lif_step(xv.z, alpha, beta, vth, mem, vdiff, spk);
        shrow[q*4 + 3] = lif_step(xv.w, alpha, beta, vth, mem, vdiff, spk);
    }
}

// Transposed coalesced store: instr k writes rows sub+8k (sub=0..7), each
// row 128B contiguous (off=0..7 selects the 16B column). Full-line writes.
__device__ __forceinline__ void store_tile(const float* __restrict__ sh, int sub, int off,
                                           float* __restrict__ op) {
#pragma unroll
    for (int k = 0; k < 8; ++k) {
        const float* p = sh + (sub + 8*k) * LDSW + off * 4;
        float4 s = make_float4(p[0], p[1], p[2], p[3]);
        *reinterpret_cast<float4*>(op + (size_t)(8*k) * T_LEN) = s;  // plain store
    }
}

__global__ __launch_bounds__(64) void lif_fwd_kernel(const float* __restrict__ x,
                                                     const float* __restrict__ alpha_p,
                                                     const float* __restrict__ beta_p,
                                                     const float* __restrict__ vth_p,
                                                     float* __restrict__ out,
                                                     int C, int rows) {
#pragma clang fp contract(off)
    // Requires rows % 64 == 0 (true: B*C = 16384): the LDS transpose needs
    // all 64 lanes of the wave active.
    __shared__ float sh[64 * LDSW];                 // 8448 B

    const int lane = threadIdx.x;
    const int row0 = blockIdx.x * 64;
    const int row  = row0 + lane;
    if (row >= rows) return;

    const float alpha = alpha_p[0];
    const float beta  = beta_p[0];
    const float vth   = vth_p[(unsigned)row % (unsigned)C];

    const float4* __restrict__ xq = reinterpret_cast<const float4*>(x + (size_t)row * T_LEN);
    float* __restrict__ shrow = sh + lane * LDSW;   // LDS write row
    const int sub = lane >> 3;                      // 0..7: row-in-group
    const int off = lane & 7;                       // 0..7: 16B column
    float* __restrict__ outp = out + (size_t)(row0 + sub) * T_LEN + off * 4;

    float mem = 0.0f, vdiff = 0.0f;
    bool  spk = false;                              // vdiff only read when spk
    float4 A[NQ], B[NQ];

    // Source-level double buffer: next tile's loads are issued before the
    // current tile's compute. sched_barrier(0) marks the intended split
    // (compile-time only; correctness is entirely standard C++).
    load_tile(A, xq);                               // tile 0
    int t = 0;
    for (int i = 0; i < 30; ++i) {                  // tiles 0..59
        load_tile(B, xq + (size_t)(t + 1) * NQ);
        __builtin_amdgcn_sched_barrier(0);
        compute_tile<NQ>(A, shrow, alpha, beta, vth, mem, vdiff, spk);
        store_tile(sh, sub, off, outp + (size_t)t * CH);
        ++t;
        load_tile(A, xq + (size_t)(t + 1) * NQ);
        __builtin_amdgcn_sched_barrier(0);
        compute_tile<NQ>(B, shrow, alpha, beta, vth, mem, vdiff, spk);
        store_tile(sh, sub, off, outp + (size_t)t * CH);
        ++t;
    }
    // t == 60; A holds tile 60.
    load_tile(B, xq + (size_t)61 * NQ);
    __builtin_amdgcn_sched_barrier(0);
    compute_tile<NQ>(A, shrow, alpha, beta, vth, mem, vdiff, spk);
    store_tile(sh, sub, off, outp + (size_t)60 * CH);

    load_tail(A, xq + (size_t)62 * NQ);             // steps 1984..1999
    __builtin_amdgcn_sched_barrier(0);
    compute_tile<NQ>(B, shrow, alpha, beta, vth, mem, vdiff, spk);
    store_tile(sh, sub, off, outp + (size_t)61 * CH);

    compute_tile<TAILQ>(A, shrow, alpha, beta, vth, mem, vdiff, spk);
    {   // tail store: 16 steps -> 64B/row, 4 lanes/row, 16 rows/instr, 4 instrs
        const int subt = lane >> 2;                 // 0..15
        const int offt = lane & 3;                  // 0..3
        float* opt = out + (size_t)(row0 + subt) * T_LEN + NFULL * CH + offt * 4;
#pragma unroll
        for (int k = 0; k < 4; ++k) {
            const float* p = sh + (subt + 16*k) * LDSW + offt * 4;
            float4 s = make_float4(p[0], p[1], p[2], p[3]);
            *reinterpret_cast<float4*>(opt + (size_t)(16*k) * T_LEN) = s;
        }
    }
}

extern "C" void kernel_launch(void* const* d_in, const int* in_sizes, int n_in,
                              void* d_out, int out_size, void* d_ws, size_t ws_size,
                              hipStream_t stream) {
    const float* x     = (const float*)d_in[0];
    const float* alpha = (const float*)d_in[1];
    const float* beta  = (const float*)d_in[2];
    const float* vth   = (const float*)d_in[3];
    float* out = (float*)d_out;

    const int C    = in_sizes[3];            // 256
    const int rows = in_sizes[0] / T_LEN;    // B*C = 16384

    dim3 grid((rows + 63) / 64), block(64);
    lif_fwd_kernel<<<grid, block, 0, stream>>>(x, alpha, beta, vth, out, C, rows);
}